// Round 14
// baseline (822.579 us; speedup 1.0000x reference)
//
#include <hip/hip_runtime.h>
#include <cstdint>
#include <cstddef>

#define BB 2
#define QQ 2048
#define KK_ 2048
#define HH 16
#define DD 64
#define DVV 64

static constexpr size_t CTX_ELEMS = (size_t)BB * QQ * HH * DVV;  // 4,194,304
#define LOG2E 1.44269504088896f
#define QSCALE (LOG2E / 8.0f)

typedef _Float16 f16x8 __attribute__((ext_vector_type(8)));
typedef _Float16 f16x4 __attribute__((ext_vector_type(4)));
typedef _Float16 f16x2 __attribute__((ext_vector_type(2)));
typedef float    f32x4 __attribute__((ext_vector_type(4)));

__device__ __forceinline__ float fexp2(float x) {
  float r;
  asm("v_exp_f32 %0, %1" : "=v"(r) : "v"(x));
  return r;
}

// Streaming store: nt = evict-first / no-LLC-pollute hint, still L2-merged
// (unlike __builtin_nontemporal_store's no-allocate mode that broke r4).
__device__ __forceinline__ void nt_store(float* p, f32x4 v) {
  asm volatile("global_store_dwordx4 %0, %1, off nt"
               :: "v"(p), "v"(v) : "memory");
}

// workspace layout (float offsets)
#define RQ_OFF    0        // [B][H][Q]  0.125*||q_row||
#define KPART_OFF 65536    // [B*H][8]   partial max ||k_row|| per chunk
#define M_OFF     65792    // [B][H][Q]  upper bound M per row

// ---------------------------------------------------------------------------
// Prep A: per (b,h,chunk): rq rows + partial kmax (over valid k only).
// ---------------------------------------------------------------------------
__global__ __launch_bounds__(256)
void prep_norms(const float* __restrict__ qs, const float* __restrict__ ks,
                const int* __restrict__ vlen, float* __restrict__ ws) {
  float* rq    = ws + RQ_OFF;
  float* kpart = ws + KPART_OFF;
  const int id = blockIdx.x;            // 0..255
  const int bh = id & 31, c = id >> 5;  // chunk 0..7
  const int h = bh & 15, b = bh >> 4;
  const int vl = vlen[b];
  const int t = threadIdx.x;
  const int grp = t >> 4, l16 = t & 15;
  const int w = t >> 6, l = t & 63;
  __shared__ float red[4];
  float km2 = 0.f;                      // max squared norm
  const int base = c * 256;
  for (int i = 0; i < 16; ++i) {
    const int r = base + i * 16 + grp;
    {
      const float4 v = *(const float4*)(qs + ((size_t)(b * QQ + r) * HH + h) * DD + l16 * 4);
      float s = v.x * v.x + v.y * v.y + v.z * v.z + v.w * v.w;
      s += __shfl_xor(s, 1); s += __shfl_xor(s, 2);
      s += __shfl_xor(s, 4); s += __shfl_xor(s, 8);
      if (l16 == 0) rq[(size_t)(b * HH + h) * QQ + r] = sqrtf(s) * 0.125f;
    }
    if (r < vl) {
      const float4 v = *(const float4*)(ks + ((size_t)(b * KK_ + r) * HH + h) * DD + l16 * 4);
      float s = v.x * v.x + v.y * v.y + v.z * v.z + v.w * v.w;
      s += __shfl_xor(s, 1); s += __shfl_xor(s, 2);
      s += __shfl_xor(s, 4); s += __shfl_xor(s, 8);
      km2 = fmaxf(km2, s);
    }
  }
  km2 = fmaxf(km2, __shfl_xor(km2, 16));
  km2 = fmaxf(km2, __shfl_xor(km2, 32));
  if (l == 0) red[w] = km2;
  __syncthreads();
  if (t == 0)
    kpart[bh * 8 + c] = sqrtf(fmaxf(fmaxf(red[0], red[1]), fmaxf(red[2], red[3])));
}

// ---------------------------------------------------------------------------
// Prep B: per (b,q): Brow = max_{k<vl} bias[q,k]; M[b,h,q] = rq*kmax + Brow.
// ---------------------------------------------------------------------------
__global__ __launch_bounds__(256)
void prep_m(const float* __restrict__ bias, const int* __restrict__ vlen,
            float* __restrict__ ws) {
  const float* rq    = ws + RQ_OFF;
  const float* kpart = ws + KPART_OFF;
  float* M = ws + M_OFF;
  const int id = blockIdx.x;            // 0..1023
  const int b = id >> 9;
  const int qb = (id & 511) * 4;
  const int t = threadIdx.x, w = t >> 6, l = t & 63;
  const int q = qb + w;
  const int vl = vlen[b];
  float m = -3e38f;
  for (int k0 = l * 4; k0 < vl; k0 += 256) {
    const float4 v = *(const float4*)(bias + (size_t)q * KK_ + k0);
    m = fmaxf(m, (k0 + 0 < vl) ? v.x : -3e38f);
    m = fmaxf(m, (k0 + 1 < vl) ? v.y : -3e38f);
    m = fmaxf(m, (k0 + 2 < vl) ? v.z : -3e38f);
    m = fmaxf(m, (k0 + 3 < vl) ? v.w : -3e38f);
  }
#pragma unroll
  for (int off = 1; off < 64; off <<= 1) m = fmaxf(m, __shfl_xor(m, off));
  if (l < 16) {
    const int h = l;
    float kmx = 0.f;
#pragma unroll
    for (int cc = 0; cc < 8; ++cc) kmx = fmaxf(kmx, kpart[(b * HH + h) * 8 + cc]);
    M[(size_t)(b * HH + h) * QQ + q] = rq[(size_t)(b * HH + h) * QQ + q] * kmx + m;
  }
}

// ---------------------------------------------------------------------------
// Main fused kernel (r10 structure). wg = (b,h, 128 q-rows), 512 thr (8 waves,
// 16 q each). K-step 128 (paired 64-row buffers, dbuf pairs) -> ONE barrier
// per 128 k. exp2 folding (fma + v_exp_f32 per element). Transposed-S MFMA:
// lane (fr,g) holds P^T[k][q] = B-frag of 16x16x16f16 -> PV from registers.
// NEW: attn + zero-fill stores use `nt` streaming hint so the 537 MB write
// stream doesn't evict K/V/bias from L3 (r7 showed FETCH 315 MB vs 65 MB of
// inputs -> L3 thrash).
// ---------------------------------------------------------------------------
__global__ __launch_bounds__(512, 4)
void fused_attn(const float* __restrict__ qs, const float* __restrict__ ks,
                const float* __restrict__ vs, const float* __restrict__ bias,
                const int* __restrict__ vlen, const float* __restrict__ ws,
                float* __restrict__ dout) {
  float* ctx  = dout;
  float* attn = dout + CTX_ELEMS;
  const float* Mbuf = ws + M_OFF;

  // XCD swizzle: XCD x owns q-tiles {2x,2x+1} x all 32 bh (bias 2MB/XCD in L2)
  const int x   = blockIdx.x;           // 0..511
  const int xcd = x & 7;
  const int j   = x >> 3;               // 0..63
  const int qt  = xcd * 2 + (j & 1);    // 0..15 (128-row tiles)
  const int bh  = j >> 1;               // 0..31
  const int h   = bh & 15, b = bh >> 4;
  const int vl  = vlen[b];
  const int ntv = (vl + 63) >> 6;       // valid 64-tiles
  const int np  = (ntv + 1) >> 1;       // 128-wide pairs (may pad 1 tile)

  const int t = threadIdx.x;
  const int w = t >> 6, l = t & 63, fr = l & 15, g = l >> 4;
  const int q0 = qt * 128, qw = q0 + w * 16;
  const int myq = qw + fr;

  __shared__ _Float16 KS[4][64][72];  // K: two pairs x two 64-row halves
  __shared__ _Float16 VS[4][64][72];  // V^T: same structure

  // ---- zero-fill attn tail beyond processed range (streaming stores) ----
  {
    const int row = t >> 2;             // 0..127
    const int c0  = (t & 3) << 4;
    float* ap = attn + ((size_t)(b * HH + h) * QQ + q0 + row) * KK_ + c0;
    const f32x4 z = {0.f, 0.f, 0.f, 0.f};
    for (int k0 = np * 128; k0 < KK_; k0 += 64) {
#pragma unroll
      for (int i = 0; i < 4; ++i) nt_store(ap + k0 + i * 4, z);
    }
  }

  // ---- Q B-fragment in registers, pre-scaled by log2e/8 ----
  f16x8 bq[2];
  {
    const float* qp = qs + ((size_t)(b * QQ + myq) * HH + h) * DD + g * 8;
#pragma unroll
    for (int kk = 0; kk < 2; ++kk) {
      const float4 f0 = *(const float4*)(qp + kk * 32);
      const float4 f1 = *(const float4*)(qp + kk * 32 + 4);
      f16x8 v;
      v[0] = (_Float16)(f0.x * QSCALE); v[1] = (_Float16)(f0.y * QSCALE);
      v[2] = (_Float16)(f0.z * QSCALE); v[3] = (_Float16)(f0.w * QSCALE);
      v[4] = (_Float16)(f1.x * QSCALE); v[5] = (_Float16)(f1.y * QSCALE);
      v[6] = (_Float16)(f1.z * QSCALE); v[7] = (_Float16)(f1.w * QSCALE);
      bq[kk] = v;
    }
  }

  const float Mq2 = Mbuf[(size_t)(b * HH + h) * QQ + myq] * LOG2E;
  const float* biasq = bias + (size_t)myq * KK_;
  float* attnq = attn + ((size_t)(b * HH + h) * QQ + myq) * KK_;

  // staging: K 128x64 -> row t>>2, 16 cols (t&3)*16; V pairs per half
  const int krow = t >> 2, kc0 = (t & 3) << 4;
  const int h64 = t >> 8;               // V half 0/1
  const int tt = t & 255;
  const int rho = tt & 31, dlt = tt >> 5;  // dlt 0..7

#define KADDR(k) (ks + ((size_t)(b * KK_ + (k)) * HH + h) * DD)
#define VADDR(k) (vs + ((size_t)(b * KK_ + (k)) * HH + h) * DVV)

#define LOAD_K2(k0arg)                                     \
  do {                                                     \
    const float* kp = KADDR((k0arg) + krow) + kc0;         \
    _Pragma("unroll") for (int i = 0; i < 4; ++i)          \
      kr[i] = ((const float4*)kp)[i];                      \
  } while (0)

#define STORE_K2(pb2)                                      \
  do {                                                     \
    const int khalf = (pb2) + (krow >> 6);                 \
    const int krw = krow & 63;                             \
    _Pragma("unroll") for (int i = 0; i < 4; ++i) {        \
      f16x4 hv;                                            \
      hv[0] = (_Float16)kr[i].x; hv[1] = (_Float16)kr[i].y;\
      hv[2] = (_Float16)kr[i].z; hv[3] = (_Float16)kr[i].w;\
      *(f16x4*)&KS[khalf][krw][kc0 + i * 4] = hv;          \
    }                                                      \
  } while (0)

#define LOAD_V2(k0arg)                                     \
  do {                                                     \
    const float* vp0 = VADDR((k0arg) + h64 * 64 + 2 * rho) + dlt * 8; \
    vr[0] = ((const float4*)vp0)[0];                       \
    vr[1] = ((const float4*)vp0)[1];                       \
    const float* vp1 = VADDR((k0arg) + h64 * 64 + 2 * rho + 1) + dlt * 8; \
    vr[2] = ((const float4*)vp1)[0];                       \
    vr[3] = ((const float4*)vp1)[1];                       \
  } while (0)

#define STORE_V2(pb2)                                      \
  do {                                                     \
    const float a0[8] = {vr[0].x, vr[0].y, vr[0].z, vr[0].w,\
                         vr[1].x, vr[1].y, vr[1].z, vr[1].w};\
    const float a1[8] = {vr[2].x, vr[2].y, vr[2].z, vr[2].w,\
                         vr[3].x, vr[3].y, vr[3].z, vr[3].w};\
    _Pragma("unroll") for (int i = 0; i < 8; ++i) {        \
      f16x2 pk; pk[0] = (_Float16)a0[i]; pk[1] = (_Float16)a1[i];\
      *(f16x2*)&VS[(pb2) + h64][dlt * 8 + i][2 * rho] = pk;\
    }                                                      \
  } while (0)

  float4 kr[4];
  float4 vr[4];

  // ================= PASS 1: lsum (1 barrier per 128 k) ======================
  LOAD_K2(0);
  STORE_K2(0);
  __syncthreads();

  float lsum = 0.f;
  for (int ip = 0; ip < np; ++ip) {
    const int pb2 = (ip & 1) << 1;
    const bool pre = (ip + 1 < np);
    const bool mpair = (ip == np - 1);
    if (pre) LOAD_K2((ip + 1) * 128);
#pragma unroll
    for (int hf = 0; hf < 2; ++hf) {
#pragma unroll
      for (int c = 0; c < 4; ++c) {
        const int kb = ip * 128 + hf * 64 + c * 16 + g * 4;
        const float4 bz = *(const float4*)(biasq + kb);
        const f16x8 ka0 = *(const f16x8*)&KS[pb2 + hf][c * 16 + fr][g * 8];
        const f16x8 ka1 = *(const f16x8*)&KS[pb2 + hf][c * 16 + fr][32 + g * 8];
        f32x4 acc = {-Mq2, -Mq2, -Mq2, -Mq2};
        acc = __builtin_amdgcn_mfma_f32_16x16x32_f16(ka0, bq[0], acc, 0, 0, 0);
        acc = __builtin_amdgcn_mfma_f32_16x16x32_f16(ka1, bq[1], acc, 0, 0, 0);
        float e[4];
#pragma unroll
        for (int r = 0; r < 4; ++r) e[r] = fexp2(fmaf(bz[r], LOG2E, acc[r]));
        if (mpair) {
#pragma unroll
          for (int r = 0; r < 4; ++r) e[r] = (kb + r < vl) ? e[r] : 0.f;
        }
        lsum += (e[0] + e[1]) + (e[2] + e[3]);
      }
    }
    if (pre) STORE_K2(pb2 ^ 2);
    __syncthreads();             // ONE barrier per 128 k
  }
  lsum += __shfl_xor(lsum, 16);
  lsum += __shfl_xor(lsum, 32);
  const float ci = -__log2f(lsum) - Mq2;   // pass-2 C-init: log2(il) - M*log2e

  // ================= PASS 2: attn write + PV (1 barrier per 128 k) ===========
  f32x4 accv[4];   // ctx^T: col=q(fr), row=dv(g*4+reg)
#pragma unroll
  for (int n = 0; n < 4; ++n) accv[n] = (f32x4){0.f, 0.f, 0.f, 0.f};

  LOAD_K2(0);
  LOAD_V2(0);
  STORE_K2(0);
  STORE_V2(0);
  __syncthreads();

  for (int ip = 0; ip < np; ++ip) {
    const int pb2 = (ip & 1) << 1;
    const bool pre = (ip + 1 < np);
    const bool mpair = (ip == np - 1);
    if (pre) {
      LOAD_K2((ip + 1) * 128);
      LOAD_V2((ip + 1) * 128);
    }
#pragma unroll
    for (int hf = 0; hf < 2; ++hf) {
#pragma unroll
      for (int c = 0; c < 4; ++c) {
        const int kb = ip * 128 + hf * 64 + c * 16 + g * 4;
        const float4 bz = *(const float4*)(biasq + kb);
        const f16x8 ka0 = *(const f16x8*)&KS[pb2 + hf][c * 16 + fr][g * 8];
        const f16x8 ka1 = *(const f16x8*)&KS[pb2 + hf][c * 16 + fr][32 + g * 8];
        f32x4 acc = {ci, ci, ci, ci};
        acc = __builtin_amdgcn_mfma_f32_16x16x32_f16(ka0, bq[0], acc, 0, 0, 0);
        acc = __builtin_amdgcn_mfma_f32_16x16x32_f16(ka1, bq[1], acc, 0, 0, 0);
        f32x4 pv;
#pragma unroll
        for (int r = 0; r < 4; ++r) pv[r] = fexp2(fmaf(bz[r], LOG2E, acc[r]));
        if (mpair) {
#pragma unroll
          for (int r = 0; r < 4; ++r) pv[r] = (kb + r < vl) ? pv[r] : 0.f;
        }
        nt_store(attnq + kb, pv);      // streaming store: don't pollute L3
        // P^T fragment = B-operand of 16x16x16f16 (k=g*4+e, n=fr)
        f16x4 ph;
#pragma unroll
        for (int r = 0; r < 4; ++r) ph[r] = (_Float16)pv[r];
#pragma unroll
        for (int n = 0; n < 4; ++n) {
          const f16x4 va = *(const f16x4*)&VS[pb2 + hf][n * 16 + fr][c * 16 + g * 4];
          accv[n] = __builtin_amdgcn_mfma_f32_16x16x16f16(va, ph, accv[n], 0, 0, 0);
        }
      }
    }
    if (pre) {
      STORE_K2(pb2 ^ 2);
      STORE_V2(pb2 ^ 2);
    }
    __syncthreads();             // ONE barrier per 128 k
  }

  // ---- ctx store: q = myq, dv = n*16 + g*4 (+r contiguous -> float4) ----
#pragma unroll
  for (int n = 0; n < 4; ++n) {
    const size_t o = ((size_t)(b * QQ + myq) * HH + h) * DVV + n * 16 + g * 4;
    *(f32x4*)(ctx + o) = accv[n];
  }
#undef KADDR
#undef VADDR
#undef LOAD_K2
#undef STORE_K2
#undef LOAD_V2
#undef STORE_V2
}

// ---------------------------------------------------------------------------
extern "C" void kernel_launch(void* const* d_in, const int* in_sizes, int n_in,
                              void* d_out, int out_size, void* d_ws, size_t ws_size,
                              hipStream_t stream) {
  (void)in_sizes; (void)n_in; (void)ws_size; (void)out_size;
  const float* qs   = (const float*)d_in[0];
  const float* ks   = (const float*)d_in[1];
  const float* vs   = (const float*)d_in[2];
  const float* bias = (const float*)d_in[3];
  const int*   vlen = (const int*)d_in[4];
  float* out = (float*)d_out;
  float* ws  = (float*)d_ws;

  prep_norms<<<dim3(256), dim3(256), 0, stream>>>(qs, ks, vlen, ws);
  prep_m<<<dim3(1024), dim3(256), 0, stream>>>(bias, vlen, ws);
  fused_attn<<<dim3(512), dim3(512), 0, stream>>>(qs, ks, vs, bias, vlen, ws, out);
}

// Round 15
// 210.136 us; speedup vs baseline: 3.9145x; 3.9145x over previous
//
#include <hip/hip_runtime.h>
#include <cstdint>
#include <cstddef>

#define BB 2
#define QQ 2048
#define KK_ 2048
#define HH 16
#define DD 64
#define DVV 64

static constexpr size_t CTX_ELEMS = (size_t)BB * QQ * HH * DVV;  // 4,194,304
#define LOG2E 1.44269504088896f
#define QSCALE (LOG2E / 8.0f)

typedef _Float16 f16x8 __attribute__((ext_vector_type(8)));
typedef _Float16 f16x4 __attribute__((ext_vector_type(4)));
typedef _Float16 f16x2 __attribute__((ext_vector_type(2)));
typedef float    f32x4 __attribute__((ext_vector_type(4)));

__device__ __forceinline__ float fexp2(float x) {
  float r;
  asm("v_exp_f32 %0, %1" : "=v"(r) : "v"(x));
  return r;
}

// workspace layout (float offsets)
#define RQ_OFF    0        // [B][H][Q]  0.125*||q_row||
#define KPART_OFF 65536    // [B*H][8]   partial max ||k_row|| per chunk
#define M_OFF     65792    // [B][H][Q]  upper bound M per row

// ---------------------------------------------------------------------------
// Prep A: per (b,h,chunk): rq rows + partial kmax (over valid k only).
// ---------------------------------------------------------------------------
__global__ __launch_bounds__(256)
void prep_norms(const float* __restrict__ qs, const float* __restrict__ ks,
                const int* __restrict__ vlen, float* __restrict__ ws) {
  float* rq    = ws + RQ_OFF;
  float* kpart = ws + KPART_OFF;
  const int id = blockIdx.x;            // 0..255
  const int bh = id & 31, c = id >> 5;  // chunk 0..7
  const int h = bh & 15, b = bh >> 4;
  const int vl = vlen[b];
  const int t = threadIdx.x;
  const int grp = t >> 4, l16 = t & 15;
  const int w = t >> 6, l = t & 63;
  __shared__ float red[4];
  float km2 = 0.f;                      // max squared norm
  const int base = c * 256;
  for (int i = 0; i < 16; ++i) {
    const int r = base + i * 16 + grp;
    {
      const float4 v = *(const float4*)(qs + ((size_t)(b * QQ + r) * HH + h) * DD + l16 * 4);
      float s = v.x * v.x + v.y * v.y + v.z * v.z + v.w * v.w;
      s += __shfl_xor(s, 1); s += __shfl_xor(s, 2);
      s += __shfl_xor(s, 4); s += __shfl_xor(s, 8);
      if (l16 == 0) rq[(size_t)(b * HH + h) * QQ + r] = sqrtf(s) * 0.125f;
    }
    if (r < vl) {
      const float4 v = *(const float4*)(ks + ((size_t)(b * KK_ + r) * HH + h) * DD + l16 * 4);
      float s = v.x * v.x + v.y * v.y + v.z * v.z + v.w * v.w;
      s += __shfl_xor(s, 1); s += __shfl_xor(s, 2);
      s += __shfl_xor(s, 4); s += __shfl_xor(s, 8);
      km2 = fmaxf(km2, s);
    }
  }
  km2 = fmaxf(km2, __shfl_xor(km2, 16));
  km2 = fmaxf(km2, __shfl_xor(km2, 32));
  if (l == 0) red[w] = km2;
  __syncthreads();
  if (t == 0)
    kpart[bh * 8 + c] = sqrtf(fmaxf(fmaxf(red[0], red[1]), fmaxf(red[2], red[3])));
}

// ---------------------------------------------------------------------------
// Prep B: per (b,q): Brow = max_{k<vl} bias[q,k]; M[b,h,q] = rq*kmax + Brow.
// ---------------------------------------------------------------------------
__global__ __launch_bounds__(256)
void prep_m(const float* __restrict__ bias, const int* __restrict__ vlen,
            float* __restrict__ ws) {
  const float* rq    = ws + RQ_OFF;
  const float* kpart = ws + KPART_OFF;
  float* M = ws + M_OFF;
  const int id = blockIdx.x;            // 0..1023
  const int b = id >> 9;
  const int qb = (id & 511) * 4;
  const int t = threadIdx.x, w = t >> 6, l = t & 63;
  const int q = qb + w;
  const int vl = vlen[b];
  float m = -3e38f;
  for (int k0 = l * 4; k0 < vl; k0 += 256) {
    const float4 v = *(const float4*)(bias + (size_t)q * KK_ + k0);
    m = fmaxf(m, (k0 + 0 < vl) ? v.x : -3e38f);
    m = fmaxf(m, (k0 + 1 < vl) ? v.y : -3e38f);
    m = fmaxf(m, (k0 + 2 < vl) ? v.z : -3e38f);
    m = fmaxf(m, (k0 + 3 < vl) ? v.w : -3e38f);
  }
#pragma unroll
  for (int off = 1; off < 64; off <<= 1) m = fmaxf(m, __shfl_xor(m, off));
  if (l < 16) {
    const int h = l;
    float kmx = 0.f;
#pragma unroll
    for (int cc = 0; cc < 8; ++cc) kmx = fmaxf(kmx, kpart[(b * HH + h) * 8 + cc]);
    M[(size_t)(b * HH + h) * QQ + q] = rq[(size_t)(b * HH + h) * QQ + q] * kmx + m;
  }
}

// ---------------------------------------------------------------------------
// Main fused kernel. wg = (b,h, 128 q-rows), 512 thr (8 waves, 16 q each).
// Pass 1: r10 structure (K pairs double-buffered across SB[0..3], 1 barrier
// per 128 k). Pass 2: K/V single-buffered pair in SB[0..1]/SB[2..3] +
// LDS-STAGED ATTN STORES: P stashed as f16 into Pst[128][136], then a store
// phase writes 32thr x 16B = 512B full-line runs per row (fill-kernel-style
// coalescing) instead of 16 scattered 64B half-lines per wave.
// exp2 folding; transposed-S MFMA; P^T-register PV; last-pair-only masking.
// ---------------------------------------------------------------------------
__global__ __launch_bounds__(512, 4)
void fused_attn(const float* __restrict__ qs, const float* __restrict__ ks,
                const float* __restrict__ vs, const float* __restrict__ bias,
                const int* __restrict__ vlen, const float* __restrict__ ws,
                float* __restrict__ dout) {
  float* ctx  = dout;
  float* attn = dout + CTX_ELEMS;
  const float* Mbuf = ws + M_OFF;

  // XCD swizzle: XCD x owns q-tiles {2x,2x+1} x all 32 bh (bias 2MB/XCD in L2)
  const int x   = blockIdx.x;           // 0..511
  const int xcd = x & 7;
  const int j   = x >> 3;               // 0..63
  const int qt  = xcd * 2 + (j & 1);    // 0..15 (128-row tiles)
  const int bh  = j >> 1;               // 0..31
  const int h   = bh & 15, b = bh >> 4;
  const int vl  = vlen[b];
  const int ntv = (vl + 63) >> 6;       // valid 64-tiles
  const int np  = (ntv + 1) >> 1;       // 128-wide pairs (may pad 1 tile)

  const int t = threadIdx.x;
  const int w = t >> 6, l = t & 63, fr = l & 15, g = l >> 4;
  const int q0 = qt * 128, qw = q0 + w * 16;
  const int myq = qw + fr;

  __shared__ _Float16 SB[4][64][72];    // pass1: K dbuf pairs; pass2: K|V
  __shared__ _Float16 Pst[128][136];    // P stage tile (f16), 272B row stride

  // ---- zero-fill attn tail beyond processed range (contiguous mapping) ----
  {
    float* ap = attn + ((size_t)(b * HH + h) * QQ + q0) * KK_;
    const f32x4 z = {0.f, 0.f, 0.f, 0.f};
    const int c0f = np * 128;
#pragma unroll
    for (int i = 0; i < 8; ++i) {
      const int row = (t >> 5) + i * 16;
      float* rp = ap + (size_t)row * KK_;
      for (int k0 = c0f + (t & 31) * 4; k0 < KK_; k0 += 128)
        *(f32x4*)(rp + k0) = z;
    }
  }

  // ---- Q B-fragment in registers, pre-scaled by log2e/8 ----
  f16x8 bq[2];
  {
    const float* qp = qs + ((size_t)(b * QQ + myq) * HH + h) * DD + g * 8;
#pragma unroll
    for (int kk = 0; kk < 2; ++kk) {
      const float4 f0 = *(const float4*)(qp + kk * 32);
      const float4 f1 = *(const float4*)(qp + kk * 32 + 4);
      f16x8 v;
      v[0] = (_Float16)(f0.x * QSCALE); v[1] = (_Float16)(f0.y * QSCALE);
      v[2] = (_Float16)(f0.z * QSCALE); v[3] = (_Float16)(f0.w * QSCALE);
      v[4] = (_Float16)(f1.x * QSCALE); v[5] = (_Float16)(f1.y * QSCALE);
      v[6] = (_Float16)(f1.z * QSCALE); v[7] = (_Float16)(f1.w * QSCALE);
      bq[kk] = v;
    }
  }

  const float Mq2 = Mbuf[(size_t)(b * HH + h) * QQ + myq] * LOG2E;
  const float* biasq = bias + (size_t)myq * KK_;

  // staging: K 128x64 -> row t>>2, 16 cols (t&3)*16; V pairs per half
  const int krow = t >> 2, kc0 = (t & 3) << 4;
  const int h64 = t >> 8;               // V half 0/1
  const int tt = t & 255;
  const int rho = tt & 31, dlt = tt >> 5;  // dlt 0..7

#define KADDR(k) (ks + ((size_t)(b * KK_ + (k)) * HH + h) * DD)
#define VADDR(k) (vs + ((size_t)(b * KK_ + (k)) * HH + h) * DVV)

#define LOAD_K2(k0arg)                                     \
  do {                                                     \
    const float* kp = KADDR((k0arg) + krow) + kc0;         \
    _Pragma("unroll") for (int i = 0; i < 4; ++i)          \
      kr[i] = ((const float4*)kp)[i];                      \
  } while (0)

#define STORE_K2(base)                                     \
  do {                                                     \
    const int khalf = (base) + (krow >> 6);                \
    const int krw = krow & 63;                             \
    _Pragma("unroll") for (int i = 0; i < 4; ++i) {        \
      f16x4 hv;                                            \
      hv[0] = (_Float16)kr[i].x; hv[1] = (_Float16)kr[i].y;\
      hv[2] = (_Float16)kr[i].z; hv[3] = (_Float16)kr[i].w;\
      *(f16x4*)&SB[khalf][krw][kc0 + i * 4] = hv;          \
    }                                                      \
  } while (0)

#define LOAD_V2(k0arg)                                     \
  do {                                                     \
    const float* vp0 = VADDR((k0arg) + h64 * 64 + 2 * rho) + dlt * 8; \
    vr[0] = ((const float4*)vp0)[0];                       \
    vr[1] = ((const float4*)vp0)[1];                       \
    const float* vp1 = VADDR((k0arg) + h64 * 64 + 2 * rho + 1) + dlt * 8; \
    vr[2] = ((const float4*)vp1)[0];                       \
    vr[3] = ((const float4*)vp1)[1];                       \
  } while (0)

#define STORE_V2(base)                                     \
  do {                                                     \
    const float a0[8] = {vr[0].x, vr[0].y, vr[0].z, vr[0].w,\
                         vr[1].x, vr[1].y, vr[1].z, vr[1].w};\
    const float a1[8] = {vr[2].x, vr[2].y, vr[2].z, vr[2].w,\
                         vr[3].x, vr[3].y, vr[3].z, vr[3].w};\
    _Pragma("unroll") for (int i = 0; i < 8; ++i) {        \
      f16x2 pk; pk[0] = (_Float16)a0[i]; pk[1] = (_Float16)a1[i];\
      *(f16x2*)&SB[(base) + h64][dlt * 8 + i][2 * rho] = pk;\
    }                                                      \
  } while (0)

  float4 kr[4];
  float4 vr[4];

  // ================= PASS 1: lsum (dbuf pairs, 1 barrier per 128 k) ==========
  LOAD_K2(0);
  STORE_K2(0);
  __syncthreads();

  float lsum = 0.f;
  for (int ip = 0; ip < np; ++ip) {
    const int pb2 = (ip & 1) << 1;
    const bool pre = (ip + 1 < np);
    const bool mpair = (ip == np - 1);
    if (pre) LOAD_K2((ip + 1) * 128);
#pragma unroll
    for (int hf = 0; hf < 2; ++hf) {
#pragma unroll
      for (int c = 0; c < 4; ++c) {
        const int kb = ip * 128 + hf * 64 + c * 16 + g * 4;
        const float4 bz = *(const float4*)(biasq + kb);
        const f16x8 ka0 = *(const f16x8*)&SB[pb2 + hf][c * 16 + fr][g * 8];
        const f16x8 ka1 = *(const f16x8*)&SB[pb2 + hf][c * 16 + fr][32 + g * 8];
        f32x4 acc = {-Mq2, -Mq2, -Mq2, -Mq2};
        acc = __builtin_amdgcn_mfma_f32_16x16x32_f16(ka0, bq[0], acc, 0, 0, 0);
        acc = __builtin_amdgcn_mfma_f32_16x16x32_f16(ka1, bq[1], acc, 0, 0, 0);
        float e[4];
#pragma unroll
        for (int r = 0; r < 4; ++r) e[r] = fexp2(fmaf(bz[r], LOG2E, acc[r]));
        if (mpair) {
#pragma unroll
          for (int r = 0; r < 4; ++r) e[r] = (kb + r < vl) ? e[r] : 0.f;
        }
        lsum += (e[0] + e[1]) + (e[2] + e[3]);
      }
    }
    if (pre) STORE_K2(pb2 ^ 2);
    __syncthreads();             // ONE barrier per 128 k
  }
  lsum += __shfl_xor(lsum, 16);
  lsum += __shfl_xor(lsum, 32);
  const float ci = -__log2f(lsum) - Mq2;   // pass-2 C-init: log2(il) - M*log2e

  // ================= PASS 2: LDS-staged attn + PV (2 barriers per 128 k) =====
  f32x4 accv[4];   // ctx^T: col=q(fr), row=dv(g*4+reg)
#pragma unroll
  for (int n = 0; n < 4; ++n) accv[n] = (f32x4){0.f, 0.f, 0.f, 0.f};

  LOAD_K2(0);
  LOAD_V2(0);
  STORE_K2(0);     // K halves -> SB[0..1]
  STORE_V2(2);     // V halves -> SB[2..3]
  __syncthreads();

  float* attnt = attn + ((size_t)(b * HH + h) * QQ + q0) * KK_;  // tile base

  for (int ip = 0; ip < np; ++ip) {
    const bool pre = (ip + 1 < np);
    const bool mpair = (ip == np - 1);
    if (pre) {
      LOAD_K2((ip + 1) * 128);
      LOAD_V2((ip + 1) * 128);
    }
#pragma unroll
    for (int hf = 0; hf < 2; ++hf) {
#pragma unroll
      for (int c = 0; c < 4; ++c) {
        const int kb = ip * 128 + hf * 64 + c * 16 + g * 4;
        const float4 bz = *(const float4*)(biasq + kb);
        const f16x8 ka0 = *(const f16x8*)&SB[hf][c * 16 + fr][g * 8];
        const f16x8 ka1 = *(const f16x8*)&SB[hf][c * 16 + fr][32 + g * 8];
        f32x4 acc = {ci, ci, ci, ci};
        acc = __builtin_amdgcn_mfma_f32_16x16x32_f16(ka0, bq[0], acc, 0, 0, 0);
        acc = __builtin_amdgcn_mfma_f32_16x16x32_f16(ka1, bq[1], acc, 0, 0, 0);
        f32x4 pv;
#pragma unroll
        for (int r = 0; r < 4; ++r) pv[r] = fexp2(fmaf(bz[r], LOG2E, acc[r]));
        if (mpair) {
#pragma unroll
          for (int r = 0; r < 4; ++r) pv[r] = (kb + r < vl) ? pv[r] : 0.f;
        }
        // P^T fragment (f16) -> PV mfma AND Pst stash (store phase later)
        f16x4 ph;
#pragma unroll
        for (int r = 0; r < 4; ++r) ph[r] = (_Float16)pv[r];
        *(f16x4*)&Pst[w * 16 + fr][hf * 64 + c * 16 + g * 4] = ph;
#pragma unroll
        for (int n = 0; n < 4; ++n) {
          const f16x4 va = *(const f16x4*)&SB[2 + hf][n * 16 + fr][c * 16 + g * 4];
          accv[n] = __builtin_amdgcn_mfma_f32_16x16x16f16(va, ph, accv[n], 0, 0, 0);
        }
      }
    }
    __syncthreads();             // Pst complete; SB reads done
    if (pre) {
      STORE_K2(0);               // restage next pair (single-buffered)
      STORE_V2(2);
    }
    // ---- coalesced store phase: 32 thr/row x 16B = 512B full-line runs ----
    {
      float* abase = attnt + ip * 128 + (t & 31) * 4;
      const int r0 = t >> 5;     // 0..15
#pragma unroll
      for (int i = 0; i < 8; ++i) {
        const int row = r0 + i * 16;
        const f16x4 ph = *(const f16x4*)&Pst[row][(t & 31) * 4];
        f32x4 pv;
#pragma unroll
        for (int r = 0; r < 4; ++r) pv[r] = (float)ph[r];
        *(f32x4*)(abase + (size_t)row * KK_) = pv;
      }
    }
    __syncthreads();             // store-phase reads + restage done
  }

  // ---- ctx store: q = myq, dv = n*16 + g*4 (+r contiguous -> float4) ----
#pragma unroll
  for (int n = 0; n < 4; ++n) {
    const size_t o = ((size_t)(b * QQ + myq) * HH + h) * DVV + n * 16 + g * 4;
    *(f32x4*)(ctx + o) = accv[n];
  }
#undef KADDR
#undef VADDR
#undef LOAD_K2
#undef STORE_K2
#undef LOAD_V2
#undef STORE_V2
}

// ---------------------------------------------------------------------------
extern "C" void kernel_launch(void* const* d_in, const int* in_sizes, int n_in,
                              void* d_out, int out_size, void* d_ws, size_t ws_size,
                              hipStream_t stream) {
  (void)in_sizes; (void)n_in; (void)ws_size; (void)out_size;
  const float* qs   = (const float*)d_in[0];
  const float* ks   = (const float*)d_in[1];
  const float* vs   = (const float*)d_in[2];
  const float* bias = (const float*)d_in[3];
  const int*   vlen = (const int*)d_in[4];
  float* out = (float*)d_out;
  float* ws  = (float*)d_ws;

  prep_norms<<<dim3(256), dim3(256), 0, stream>>>(qs, ks, vlen, ws);
  prep_m<<<dim3(1024), dim3(256), 0, stream>>>(bias, vlen, ws);
  fused_attn<<<dim3(512), dim3(512), 0, stream>>>(qs, ks, vs, bias, vlen, ws, out);
}

// Round 16
// 176.646 us; speedup vs baseline: 4.6566x; 1.1896x over previous
//
#include <hip/hip_runtime.h>
#include <cstdint>
#include <cstddef>

#define BB 2
#define QQ 2048
#define KK_ 2048
#define HH 16
#define DD 64
#define DVV 64

static constexpr size_t CTX_ELEMS = (size_t)BB * QQ * HH * DVV;  // 4,194,304
#define LOG2E 1.44269504088896f
#define QSCALE (LOG2E / 8.0f)

typedef _Float16 f16x8 __attribute__((ext_vector_type(8)));
typedef _Float16 f16x4 __attribute__((ext_vector_type(4)));
typedef _Float16 f16x2 __attribute__((ext_vector_type(2)));
typedef float    f32x4 __attribute__((ext_vector_type(4)));

__device__ __forceinline__ float fexp2(float x) {
  float r;
  asm("v_exp_f32 %0, %1" : "=v"(r) : "v"(x));
  return r;
}

// Streaming store (no-LLC-allocate). r14 showed it kills the L3 read-thrash
// (FETCH 315->113 MB) but amplified WRITE on scattered 16B stores. The store
// phase below writes full 64B sectors / 128B lines (32 lanes x 16B contig),
// so the no-allocate path should emit clean full-sector writes.
__device__ __forceinline__ void nt_store(float* p, f32x4 v) {
  asm volatile("global_store_dwordx4 %0, %1, off nt"
               :: "v"(p), "v"(v) : "memory");
}

// workspace layout (float offsets)
#define RQ_OFF    0        // [B][H][Q]  0.125*||q_row||
#define KPART_OFF 65536    // [B*H][8]   partial max ||k_row|| per chunk
#define M_OFF     65792    // [B][H][Q]  upper bound M per row

// ---------------------------------------------------------------------------
// Prep A: per (b,h,chunk): rq rows + partial kmax (over valid k only).
// ---------------------------------------------------------------------------
__global__ __launch_bounds__(256)
void prep_norms(const float* __restrict__ qs, const float* __restrict__ ks,
                const int* __restrict__ vlen, float* __restrict__ ws) {
  float* rq    = ws + RQ_OFF;
  float* kpart = ws + KPART_OFF;
  const int id = blockIdx.x;            // 0..255
  const int bh = id & 31, c = id >> 5;  // chunk 0..7
  const int h = bh & 15, b = bh >> 4;
  const int vl = vlen[b];
  const int t = threadIdx.x;
  const int grp = t >> 4, l16 = t & 15;
  const int w = t >> 6, l = t & 63;
  __shared__ float red[4];
  float km2 = 0.f;                      // max squared norm
  const int base = c * 256;
  for (int i = 0; i < 16; ++i) {
    const int r = base + i * 16 + grp;
    {
      const float4 v = *(const float4*)(qs + ((size_t)(b * QQ + r) * HH + h) * DD + l16 * 4);
      float s = v.x * v.x + v.y * v.y + v.z * v.z + v.w * v.w;
      s += __shfl_xor(s, 1); s += __shfl_xor(s, 2);
      s += __shfl_xor(s, 4); s += __shfl_xor(s, 8);
      if (l16 == 0) rq[(size_t)(b * HH + h) * QQ + r] = sqrtf(s) * 0.125f;
    }
    if (r < vl) {
      const float4 v = *(const float4*)(ks + ((size_t)(b * KK_ + r) * HH + h) * DD + l16 * 4);
      float s = v.x * v.x + v.y * v.y + v.z * v.z + v.w * v.w;
      s += __shfl_xor(s, 1); s += __shfl_xor(s, 2);
      s += __shfl_xor(s, 4); s += __shfl_xor(s, 8);
      km2 = fmaxf(km2, s);
    }
  }
  km2 = fmaxf(km2, __shfl_xor(km2, 16));
  km2 = fmaxf(km2, __shfl_xor(km2, 32));
  if (l == 0) red[w] = km2;
  __syncthreads();
  if (t == 0)
    kpart[bh * 8 + c] = sqrtf(fmaxf(fmaxf(red[0], red[1]), fmaxf(red[2], red[3])));
}

// ---------------------------------------------------------------------------
// Prep B: per (b,q): Brow = max_{k<vl} bias[q,k]; M[b,h,q] = rq*kmax + Brow.
// ---------------------------------------------------------------------------
__global__ __launch_bounds__(256)
void prep_m(const float* __restrict__ bias, const int* __restrict__ vlen,
            float* __restrict__ ws) {
  const float* rq    = ws + RQ_OFF;
  const float* kpart = ws + KPART_OFF;
  float* M = ws + M_OFF;
  const int id = blockIdx.x;            // 0..1023
  const int b = id >> 9;
  const int qb = (id & 511) * 4;
  const int t = threadIdx.x, w = t >> 6, l = t & 63;
  const int q = qb + w;
  const int vl = vlen[b];
  float m = -3e38f;
  for (int k0 = l * 4; k0 < vl; k0 += 256) {
    const float4 v = *(const float4*)(bias + (size_t)q * KK_ + k0);
    m = fmaxf(m, (k0 + 0 < vl) ? v.x : -3e38f);
    m = fmaxf(m, (k0 + 1 < vl) ? v.y : -3e38f);
    m = fmaxf(m, (k0 + 2 < vl) ? v.z : -3e38f);
    m = fmaxf(m, (k0 + 3 < vl) ? v.w : -3e38f);
  }
#pragma unroll
  for (int off = 1; off < 64; off <<= 1) m = fmaxf(m, __shfl_xor(m, off));
  if (l < 16) {
    const int h = l;
    float kmx = 0.f;
#pragma unroll
    for (int cc = 0; cc < 8; ++cc) kmx = fmaxf(kmx, kpart[(b * HH + h) * 8 + cc]);
    M[(size_t)(b * HH + h) * QQ + q] = rq[(size_t)(b * HH + h) * QQ + q] * kmx + m;
  }
}

// ---------------------------------------------------------------------------
// Main fused kernel. wg = (b,h, 128 q-rows), 512 thr (8 waves, 16 q each).
// Pass 1: r10 structure (K pairs double-buffered across SB[0..3], 1 barrier
// per 128 k). Pass 2: K/V single-buffered pair in SB[0..1]/SB[2..3] +
// LDS-STAGED ATTN STORES: P stashed as f16 into Pst[128][136], then a store
// phase writes 32thr x 16B = 512B full-line runs per row, now with `nt`
// (no-LLC-allocate) so the 537 MB write stream stops evicting K/V/bias
// from L3 (r14: FETCH 315->113 MB).
// exp2 folding; transposed-S MFMA; P^T-register PV; last-pair-only masking.
// ---------------------------------------------------------------------------
__global__ __launch_bounds__(512, 4)
void fused_attn(const float* __restrict__ qs, const float* __restrict__ ks,
                const float* __restrict__ vs, const float* __restrict__ bias,
                const int* __restrict__ vlen, const float* __restrict__ ws,
                float* __restrict__ dout) {
  float* ctx  = dout;
  float* attn = dout + CTX_ELEMS;
  const float* Mbuf = ws + M_OFF;

  // XCD swizzle: XCD x owns q-tiles {2x,2x+1} x all 32 bh (bias 2MB/XCD in L2)
  const int x   = blockIdx.x;           // 0..511
  const int xcd = x & 7;
  const int j   = x >> 3;               // 0..63
  const int qt  = xcd * 2 + (j & 1);    // 0..15 (128-row tiles)
  const int bh  = j >> 1;               // 0..31
  const int h   = bh & 15, b = bh >> 4;
  const int vl  = vlen[b];
  const int ntv = (vl + 63) >> 6;       // valid 64-tiles
  const int np  = (ntv + 1) >> 1;       // 128-wide pairs (may pad 1 tile)

  const int t = threadIdx.x;
  const int w = t >> 6, l = t & 63, fr = l & 15, g = l >> 4;
  const int q0 = qt * 128, qw = q0 + w * 16;
  const int myq = qw + fr;

  __shared__ _Float16 SB[4][64][72];    // pass1: K dbuf pairs; pass2: K|V
  __shared__ _Float16 Pst[128][136];    // P stage tile (f16), 272B row stride

  // ---- zero-fill attn tail beyond processed range (contiguous + nt) ----
  {
    float* ap = attn + ((size_t)(b * HH + h) * QQ + q0) * KK_;
    const f32x4 z = {0.f, 0.f, 0.f, 0.f};
    const int c0f = np * 128;
#pragma unroll
    for (int i = 0; i < 8; ++i) {
      const int row = (t >> 5) + i * 16;
      float* rp = ap + (size_t)row * KK_;
      for (int k0 = c0f + (t & 31) * 4; k0 < KK_; k0 += 128)
        nt_store(rp + k0, z);
    }
  }

  // ---- Q B-fragment in registers, pre-scaled by log2e/8 ----
  f16x8 bq[2];
  {
    const float* qp = qs + ((size_t)(b * QQ + myq) * HH + h) * DD + g * 8;
#pragma unroll
    for (int kk = 0; kk < 2; ++kk) {
      const float4 f0 = *(const float4*)(qp + kk * 32);
      const float4 f1 = *(const float4*)(qp + kk * 32 + 4);
      f16x8 v;
      v[0] = (_Float16)(f0.x * QSCALE); v[1] = (_Float16)(f0.y * QSCALE);
      v[2] = (_Float16)(f0.z * QSCALE); v[3] = (_Float16)(f0.w * QSCALE);
      v[4] = (_Float16)(f1.x * QSCALE); v[5] = (_Float16)(f1.y * QSCALE);
      v[6] = (_Float16)(f1.z * QSCALE); v[7] = (_Float16)(f1.w * QSCALE);
      bq[kk] = v;
    }
  }

  const float Mq2 = Mbuf[(size_t)(b * HH + h) * QQ + myq] * LOG2E;
  const float* biasq = bias + (size_t)myq * KK_;

  // staging: K 128x64 -> row t>>2, 16 cols (t&3)*16; V pairs per half
  const int krow = t >> 2, kc0 = (t & 3) << 4;
  const int h64 = t >> 8;               // V half 0/1
  const int tt = t & 255;
  const int rho = tt & 31, dlt = tt >> 5;  // dlt 0..7

#define KADDR(k) (ks + ((size_t)(b * KK_ + (k)) * HH + h) * DD)
#define VADDR(k) (vs + ((size_t)(b * KK_ + (k)) * HH + h) * DVV)

#define LOAD_K2(k0arg)                                     \
  do {                                                     \
    const float* kp = KADDR((k0arg) + krow) + kc0;         \
    _Pragma("unroll") for (int i = 0; i < 4; ++i)          \
      kr[i] = ((const float4*)kp)[i];                      \
  } while (0)

#define STORE_K2(base)                                     \
  do {                                                     \
    const int khalf = (base) + (krow >> 6);                \
    const int krw = krow & 63;                             \
    _Pragma("unroll") for (int i = 0; i < 4; ++i) {        \
      f16x4 hv;                                            \
      hv[0] = (_Float16)kr[i].x; hv[1] = (_Float16)kr[i].y;\
      hv[2] = (_Float16)kr[i].z; hv[3] = (_Float16)kr[i].w;\
      *(f16x4*)&SB[khalf][krw][kc0 + i * 4] = hv;          \
    }                                                      \
  } while (0)

#define LOAD_V2(k0arg)                                     \
  do {                                                     \
    const float* vp0 = VADDR((k0arg) + h64 * 64 + 2 * rho) + dlt * 8; \
    vr[0] = ((const float4*)vp0)[0];                       \
    vr[1] = ((const float4*)vp0)[1];                       \
    const float* vp1 = VADDR((k0arg) + h64 * 64 + 2 * rho + 1) + dlt * 8; \
    vr[2] = ((const float4*)vp1)[0];                       \
    vr[3] = ((const float4*)vp1)[1];                       \
  } while (0)

#define STORE_V2(base)                                     \
  do {                                                     \
    const float a0[8] = {vr[0].x, vr[0].y, vr[0].z, vr[0].w,\
                         vr[1].x, vr[1].y, vr[1].z, vr[1].w};\
    const float a1[8] = {vr[2].x, vr[2].y, vr[2].z, vr[2].w,\
                         vr[3].x, vr[3].y, vr[3].z, vr[3].w};\
    _Pragma("unroll") for (int i = 0; i < 8; ++i) {        \
      f16x2 pk; pk[0] = (_Float16)a0[i]; pk[1] = (_Float16)a1[i];\
      *(f16x2*)&SB[(base) + h64][dlt * 8 + i][2 * rho] = pk;\
    }                                                      \
  } while (0)

  float4 kr[4];
  float4 vr[4];

  // ================= PASS 1: lsum (dbuf pairs, 1 barrier per 128 k) ==========
  LOAD_K2(0);
  STORE_K2(0);
  __syncthreads();

  float lsum = 0.f;
  for (int ip = 0; ip < np; ++ip) {
    const int pb2 = (ip & 1) << 1;
    const bool pre = (ip + 1 < np);
    const bool mpair = (ip == np - 1);
    if (pre) LOAD_K2((ip + 1) * 128);
#pragma unroll
    for (int hf = 0; hf < 2; ++hf) {
#pragma unroll
      for (int c = 0; c < 4; ++c) {
        const int kb = ip * 128 + hf * 64 + c * 16 + g * 4;
        const float4 bz = *(const float4*)(biasq + kb);
        const f16x8 ka0 = *(const f16x8*)&SB[pb2 + hf][c * 16 + fr][g * 8];
        const f16x8 ka1 = *(const f16x8*)&SB[pb2 + hf][c * 16 + fr][32 + g * 8];
        f32x4 acc = {-Mq2, -Mq2, -Mq2, -Mq2};
        acc = __builtin_amdgcn_mfma_f32_16x16x32_f16(ka0, bq[0], acc, 0, 0, 0);
        acc = __builtin_amdgcn_mfma_f32_16x16x32_f16(ka1, bq[1], acc, 0, 0, 0);
        float e[4];
#pragma unroll
        for (int r = 0; r < 4; ++r) e[r] = fexp2(fmaf(bz[r], LOG2E, acc[r]));
        if (mpair) {
#pragma unroll
          for (int r = 0; r < 4; ++r) e[r] = (kb + r < vl) ? e[r] : 0.f;
        }
        lsum += (e[0] + e[1]) + (e[2] + e[3]);
      }
    }
    if (pre) STORE_K2(pb2 ^ 2);
    __syncthreads();             // ONE barrier per 128 k
  }
  lsum += __shfl_xor(lsum, 16);
  lsum += __shfl_xor(lsum, 32);
  const float ci = -__log2f(lsum) - Mq2;   // pass-2 C-init: log2(il) - M*log2e

  // ================= PASS 2: LDS-staged attn + PV (2 barriers per 128 k) =====
  f32x4 accv[4];   // ctx^T: col=q(fr), row=dv(g*4+reg)
#pragma unroll
  for (int n = 0; n < 4; ++n) accv[n] = (f32x4){0.f, 0.f, 0.f, 0.f};

  LOAD_K2(0);
  LOAD_V2(0);
  STORE_K2(0);     // K halves -> SB[0..1]
  STORE_V2(2);     // V halves -> SB[2..3]
  __syncthreads();

  float* attnt = attn + ((size_t)(b * HH + h) * QQ + q0) * KK_;  // tile base

  for (int ip = 0; ip < np; ++ip) {
    const bool pre = (ip + 1 < np);
    const bool mpair = (ip == np - 1);
    if (pre) {
      LOAD_K2((ip + 1) * 128);
      LOAD_V2((ip + 1) * 128);
    }
#pragma unroll
    for (int hf = 0; hf < 2; ++hf) {
#pragma unroll
      for (int c = 0; c < 4; ++c) {
        const int kb = ip * 128 + hf * 64 + c * 16 + g * 4;
        const float4 bz = *(const float4*)(biasq + kb);
        const f16x8 ka0 = *(const f16x8*)&SB[hf][c * 16 + fr][g * 8];
        const f16x8 ka1 = *(const f16x8*)&SB[hf][c * 16 + fr][32 + g * 8];
        f32x4 acc = {ci, ci, ci, ci};
        acc = __builtin_amdgcn_mfma_f32_16x16x32_f16(ka0, bq[0], acc, 0, 0, 0);
        acc = __builtin_amdgcn_mfma_f32_16x16x32_f16(ka1, bq[1], acc, 0, 0, 0);
        f32x4 pv;
#pragma unroll
        for (int r = 0; r < 4; ++r) pv[r] = fexp2(fmaf(bz[r], LOG2E, acc[r]));
        if (mpair) {
#pragma unroll
          for (int r = 0; r < 4; ++r) pv[r] = (kb + r < vl) ? pv[r] : 0.f;
        }
        // P^T fragment (f16) -> PV mfma AND Pst stash (store phase later)
        f16x4 ph;
#pragma unroll
        for (int r = 0; r < 4; ++r) ph[r] = (_Float16)pv[r];
        *(f16x4*)&Pst[w * 16 + fr][hf * 64 + c * 16 + g * 4] = ph;
#pragma unroll
        for (int n = 0; n < 4; ++n) {
          const f16x4 va = *(const f16x4*)&SB[2 + hf][n * 16 + fr][c * 16 + g * 4];
          accv[n] = __builtin_amdgcn_mfma_f32_16x16x16f16(va, ph, accv[n], 0, 0, 0);
        }
      }
    }
    __syncthreads();             // Pst complete; SB reads done
    if (pre) {
      STORE_K2(0);               // restage next pair (single-buffered)
      STORE_V2(2);
    }
    // ---- coalesced store phase: 32 thr/row x 16B = 512B full-line runs ----
    {
      float* abase = attnt + ip * 128 + (t & 31) * 4;
      const int r0 = t >> 5;     // 0..15
#pragma unroll
      for (int i = 0; i < 8; ++i) {
        const int row = r0 + i * 16;
        const f16x4 ph = *(const f16x4*)&Pst[row][(t & 31) * 4];
        f32x4 pv;
#pragma unroll
        for (int r = 0; r < 4; ++r) pv[r] = (float)ph[r];
        nt_store(abase + (size_t)row * KK_, pv);   // streaming full-line store
      }
    }
    __syncthreads();             // store-phase reads + restage done
  }

  // ---- ctx store: q = myq, dv = n*16 + g*4 (+r contiguous -> float4) ----
#pragma unroll
  for (int n = 0; n < 4; ++n) {
    const size_t o = ((size_t)(b * QQ + myq) * HH + h) * DVV + n * 16 + g * 4;
    *(f32x4*)(ctx + o) = accv[n];
  }
#undef KADDR
#undef VADDR
#undef LOAD_K2
#undef STORE_K2
#undef LOAD_V2
#undef STORE_V2
}

// ---------------------------------------------------------------------------
extern "C" void kernel_launch(void* const* d_in, const int* in_sizes, int n_in,
                              void* d_out, int out_size, void* d_ws, size_t ws_size,
                              hipStream_t stream) {
  (void)in_sizes; (void)n_in; (void)ws_size; (void)out_size;
  const float* qs   = (const float*)d_in[0];
  const float* ks   = (const float*)d_in[1];
  const float* vs   = (const float*)d_in[2];
  const float* bias = (const float*)d_in[3];
  const int*   vlen = (const int*)d_in[4];
  float* out = (float*)d_out;
  float* ws  = (float*)d_ws;

  prep_norms<<<dim3(256), dim3(256), 0, stream>>>(qs, ks, vlen, ws);
  prep_m<<<dim3(1024), dim3(256), 0, stream>>>(bias, vlen, ws);
  fused_attn<<<dim3(512), dim3(512), 0, stream>>>(qs, ks, vs, bias, vlen, ws, out);
}